// Round 11
// baseline (48.294 us; speedup 1.0000x reference)
//
#include <hip/hip_runtime.h>
#include <hip/hip_bf16.h>

typedef float    f32x4  __attribute__((ext_vector_type(4)));
typedef float    f32x16 __attribute__((ext_vector_type(16)));
typedef short    s16x4  __attribute__((ext_vector_type(4)));
typedef short    s16x8  __attribute__((ext_vector_type(8)));
typedef unsigned u32x4  __attribute__((ext_vector_type(4)));
typedef __bf16   bf16x8 __attribute__((ext_vector_type(8)));

#define DEVI __device__ __forceinline__

DEVI short f2bf(float f) {
    unsigned u = __builtin_bit_cast(unsigned, f);
    u += 0x8000u;
    return (short)(u >> 16);
}
DEVI float bf2f(short s) {
    return __builtin_bit_cast(float, ((unsigned)(unsigned short)s) << 16);
}
DEVI unsigned cvt_pk_bf16(float lo, float hi) {
#if defined(__HIP_DEVICE_COMPILE__)
    unsigned r;
    asm("v_cvt_pk_bf16_f32 %0, %1, %2" : "=v"(r) : "v"(lo), "v"(hi));
    return r;
#else
    return (unsigned)(unsigned short)f2bf(lo) | ((unsigned)(unsigned short)f2bf(hi) << 16);
#endif
}

DEVI float fast_exp2(float x) {
#if defined(__HIP_DEVICE_COMPILE__) && __has_builtin(__builtin_amdgcn_exp2f)
    return __builtin_amdgcn_exp2f(x);
#else
    return exp2f(x);
#endif
}

DEVI f32x4 mfma32(s16x8 a, s16x8 b, f32x4 c) {
#if defined(__HIP_DEVICE_COMPILE__) && __has_builtin(__builtin_amdgcn_mfma_f32_16x16x32_bf16)
    return __builtin_amdgcn_mfma_f32_16x16x32_bf16(
        __builtin_bit_cast(bf16x8, a), __builtin_bit_cast(bf16x8, b), c, 0, 0, 0);
#else
    asm volatile("v_mfma_f32_16x16x32_bf16 %0, %1, %2, %0" : "+v"(c) : "v"(a), "v"(b));
    return c;
#endif
}

DEVI f32x16 mfma3216(s16x8 a, s16x8 b, f32x16 c) {
#if defined(__HIP_DEVICE_COMPILE__) && __has_builtin(__builtin_amdgcn_mfma_f32_32x32x16_bf16)
    return __builtin_amdgcn_mfma_f32_32x32x16_bf16(
        __builtin_bit_cast(bf16x8, a), __builtin_bit_cast(bf16x8, b), c, 0, 0, 0);
#else
    asm volatile("v_mfma_f32_32x32x16_bf16 %0, %1, %2, %0" : "+v"(c) : "v"(a), "v"(b));
    return c;
#endif
}

DEVI void setprio1() {
#if defined(__HIP_DEVICE_COMPILE__)
    __builtin_amdgcn_s_setprio(1);
#endif
}
DEVI void setprio0() {
#if defined(__HIP_DEVICE_COMPILE__)
    __builtin_amdgcn_s_setprio(0);
#endif
}

// -------------------------------------------------------------------------
// Kernel 1: QKV projection via MFMA (unchanged, ~4us).
//   Qg/Kg: [4][4096][64] bf16 (Q pre-scaled by log2(e)/8)
//   Vtg:   [4][64][4096] bf16
// -------------------------------------------------------------------------
__global__ __launch_bounds__(512) void qkv_proj(
    const float* __restrict__ x,
    const float* __restrict__ wq, const float* __restrict__ bq,
    const float* __restrict__ wk, const float* __restrict__ bk,
    const float* __restrict__ wv, const float* __restrict__ bv,
    short* __restrict__ Qg, short* __restrict__ Kg, short* __restrict__ Vtg)
{
    __shared__ short Xt[32 * 64];   // [l][c], slot-swizzled

    const int b  = blockIdx.x >> 7;
    const int l0 = (blockIdx.x & 127) * 32;
    const int t  = threadIdx.x;
    const float QS = 0.18033688011112042f;   // log2(e)/sqrt(64)

    {
        const int c  = t & 63;
        const int lh = (t >> 6) * 4;
        const float* xr = x + ((size_t)b * 64 + c) * 4096 + l0 + lh;
        const float4 x0 = *reinterpret_cast<const float4*>(xr);
        float xv[4] = {x0.x, x0.y, x0.z, x0.w};
        #pragma unroll
        for (int i = 0; i < 4; ++i) {
            const int l = lh + i;
            Xt[l * 64 + (((c >> 3) ^ (l & 7)) * 8) + (c & 7)] = f2bf(xv[i]);
        }
    }

    const int lane = t & 63, w = t >> 6;
    const int g = lane >> 4, col = lane & 15;
    const int o0 = (w & 3) * 16;
    const int h  = w >> 2;

    s16x8 wqf[2], wkf[2], wvf[2];
    #pragma unroll
    for (int kc = 0; kc < 2; ++kc) {
        const int cb = 8 * g + 32 * kc;
        const float4 q0 = *reinterpret_cast<const float4*>(wq + (o0 + col) * 64 + cb);
        const float4 q1 = *reinterpret_cast<const float4*>(wq + (o0 + col) * 64 + cb + 4);
        const float4 k0 = *reinterpret_cast<const float4*>(wk + (o0 + col) * 64 + cb);
        const float4 k1 = *reinterpret_cast<const float4*>(wk + (o0 + col) * 64 + cb + 4);
        const float4 v0 = *reinterpret_cast<const float4*>(wv + (o0 + col) * 64 + cb);
        const float4 v1 = *reinterpret_cast<const float4*>(wv + (o0 + col) * 64 + cb + 4);
        wqf[kc][0] = f2bf(q0.x * QS); wqf[kc][1] = f2bf(q0.y * QS);
        wqf[kc][2] = f2bf(q0.z * QS); wqf[kc][3] = f2bf(q0.w * QS);
        wqf[kc][4] = f2bf(q1.x * QS); wqf[kc][5] = f2bf(q1.y * QS);
        wqf[kc][6] = f2bf(q1.z * QS); wqf[kc][7] = f2bf(q1.w * QS);
        wkf[kc][0] = f2bf(k0.x); wkf[kc][1] = f2bf(k0.y);
        wkf[kc][2] = f2bf(k0.z); wkf[kc][3] = f2bf(k0.w);
        wkf[kc][4] = f2bf(k1.x); wkf[kc][5] = f2bf(k1.y);
        wkf[kc][6] = f2bf(k1.z); wkf[kc][7] = f2bf(k1.w);
        wvf[kc][0] = f2bf(v0.x); wvf[kc][1] = f2bf(v0.y);
        wvf[kc][2] = f2bf(v0.z); wvf[kc][3] = f2bf(v0.w);
        wvf[kc][4] = f2bf(v1.x); wvf[kc][5] = f2bf(v1.y);
        wvf[kc][6] = f2bf(v1.z); wvf[kc][7] = f2bf(v1.w);
    }
    const f32x4 bq4 = *reinterpret_cast<const f32x4*>(bq + o0 + 4 * g);
    const f32x4 bk4 = *reinterpret_cast<const f32x4*>(bk + o0 + 4 * g);
    const float bvs = bv[o0 + col];

    __syncthreads();

    {
        const int row = h * 16 + col;
        const s16x8 xf0 = *reinterpret_cast<const s16x8*>(
            &Xt[row * 64 + ((g ^ (row & 7)) * 8)]);
        const s16x8 xf1 = *reinterpret_cast<const s16x8*>(
            &Xt[row * 64 + (((g + 4) ^ (row & 7)) * 8)]);

        f32x4 qa = bq4 * QS;
        qa = mfma32(wqf[0], xf0, qa);
        qa = mfma32(wqf[1], xf1, qa);
        f32x4 ka = bk4;
        ka = mfma32(wkf[0], xf0, ka);
        ka = mfma32(wkf[1], xf1, ka);
        f32x4 va = {bvs, bvs, bvs, bvs};
        va = mfma32(xf0, wvf[0], va);
        va = mfma32(xf1, wvf[1], va);

        s16x4 qs, ks;
        #pragma unroll
        for (int r = 0; r < 4; ++r) { qs[r] = f2bf(qa[r]); ks[r] = f2bf(ka[r]); }
        const size_t qkbase = ((size_t)b * 4096 + l0 + row) * 64 + o0 + 4 * g;
        *reinterpret_cast<s16x4*>(Qg + qkbase) = qs;
        *reinterpret_cast<s16x4*>(Kg + qkbase) = ks;

        s16x4 vs;
        #pragma unroll
        for (int r = 0; r < 4; ++r) vs[r] = f2bf(va[r]);
        *reinterpret_cast<s16x4*>(
            Vtg + ((size_t)b * 64 + o0 + col) * 4096 + l0 + h * 16 + 4 * g) = vs;
    }
}

// -------------------------------------------------------------------------
// Kernel 2: fused flash attention + residual, WAVE-PRIVATE K/V streams.
// 256 blocks = 4 b x 64 q-tiles(64 rows). 512 thr = 8 waves = 2 q-subtiles
// x 4 KV streams. Each wave sweeps its 1024 j in 32 tiles of 32 j, staged
// into its OWN double-buffered LDS region (K 4KB swizzled; V 5KB, 80B-pad
// rows + permuted j-groups for exchange-free PV). ZERO barriers in the
// main loop (intra-wave vmcnt/lgkmcnt only) -> waves free-run and de-phase;
// setprio arbitrates. Fixed-max softmax (exact: |S*log2e| small). Epilogue:
// 2 barriers, LDS merge of the 4 stream partials, residual, direct out.
// LDS: 8 waves x 18KB = 144KB -> 1 block/CU, 2 free-running waves/SIMD.
// -------------------------------------------------------------------------
__global__ __launch_bounds__(512, 2) void attn_fused(
    const short* __restrict__ Qg, const short* __restrict__ Kg,
    const short* __restrict__ Vtg, const float* __restrict__ x,
    float* __restrict__ out)
{
    __shared__ short SM[73728];   // 144KB; per-wave: K 2x2048 | V 2x2560 shorts

    const int bid = blockIdx.x;
    const int wid = (bid & 7) * 32 + (bid >> 3);   // XCD-bijective (256 = 8x32)
    const int b   = wid >> 6;
    const int qt  = wid & 63;

    const int t    = threadIdx.x;
    const int w    = t >> 6;
    const int lane = t & 63;
    const int qi   = lane & 31;
    const int hi   = lane >> 5;
    const int rx   = qi & 7;
    const int kw   = w & 3;        // this wave's KV stream (1024 j)
    const int qw   = w >> 2;       // this wave's q subtile

    const int qglob = qt * 64 + qw * 32 + qi;

    // Q B-frags: qf[m] = Q[q][16m + 8hi .. +8)
    s16x8 qf[4];
    {
        const short* qp = Qg + ((size_t)b * 4096 + qglob) * 64 + 8 * hi;
        qf[0] = *reinterpret_cast<const s16x8*>(qp);
        qf[1] = *reinterpret_cast<const s16x8*>(qp + 16);
        qf[2] = *reinterpret_cast<const s16x8*>(qp + 32);
        qf[3] = *reinterpret_cast<const s16x8*>(qp + 48);
    }

    const short* Kb = Kg  + (size_t)b * 4096 * 64;
    const short* Vb = Vtg + (size_t)b * 64 * 4096;

    // ---- wave-private staging geometry ----
    // K tile: 32 rows(j) x 64 shorts(d), slot-XOR swizzle. Lane: 4 chunks,
    //   row = 8c + (lane>>3), slot = lane&7.
    // V tile: 64 rows(d) x 40 shorts (32 j + 8 pad; 80B rows = conflict-free
    //   PV reads). j-groups (4 j) permuted: dest(g) = (g&4)|((g&1)<<1)|((g&2)>>1)
    //   so PV A-frags match P's register j-order. Lane: 4 chunks,
    //   row = 16c + (lane>>2), loads j-groups {2s,2s+1}, s = lane&3.
    const int r0k = lane >> 3;
    const int sk  = lane & 7;
    const int r0v = lane >> 2;
    const int sv  = lane & 3;

    short* Kbuf = SM + w * 9216;          // [2][2048]
    short* Vbuf = SM + w * 9216 + 4096;   // [2][2560]

    int kdoff[4], vdoff0[4], vdoff1[4];
    {
        const int dest0 = ((sv & 2) << 1) | (sv & 1);
        const int dest1 = dest0 | 2;
        #pragma unroll
        for (int c = 0; c < 4; ++c) {
            kdoff[c]  = (c * 8 + r0k) * 64 + ((sk ^ (r0k & 7)) * 8);
            vdoff0[c] = (c * 16 + r0v) * 40 + dest0 * 4;
            vdoff1[c] = (c * 16 + r0v) * 40 + dest1 * 4;
        }
    }
    const short* kgb = Kb + ((size_t)kw * 1024 + r0k) * 64 + sk * 8;  // +2048/tile, +512/c
    const short* vgb = Vb + (size_t)r0v * 4096 + kw * 1024 + sv * 8;  // +32/tile, +65536/c

    // ---- prologue: stage tile 0 into buf 0 (wave-private, no barrier) ----
    s16x8 kpre[4], vpre[4];
    #pragma unroll
    for (int c = 0; c < 4; ++c) {
        kpre[c] = *reinterpret_cast<const s16x8*>(kgb + c * 512);
        vpre[c] = *reinterpret_cast<const s16x8*>(vgb + (size_t)c * 65536);
    }
    #pragma unroll
    for (int c = 0; c < 4; ++c) {
        *reinterpret_cast<s16x8*>(&Kbuf[kdoff[c]]) = kpre[c];
        s16x4 vlo = {vpre[c][0], vpre[c][1], vpre[c][2], vpre[c][3]};
        s16x4 vhi = {vpre[c][4], vpre[c][5], vpre[c][6], vpre[c][7]};
        *reinterpret_cast<s16x4*>(&Vbuf[vdoff0[c]]) = vlo;
        *reinterpret_cast<s16x4*>(&Vbuf[vdoff1[c]]) = vhi;
    }

    f32x16 oacc0 = {}, oacc1 = {};
    float lsum = 0.0f;

    #pragma unroll 2
    for (int tt = 0; tt < 32; ++tt) {
        const int cur = tt & 1;
        const short* Kl = Kbuf + cur * 2048;
        const short* Vl = Vbuf + cur * 2560;

        if (tt < 31) {   // prefetch next tile into regs (vmcnt-covered by compute)
            #pragma unroll
            for (int c = 0; c < 4; ++c) {
                kpre[c] = *reinterpret_cast<const s16x8*>(
                    kgb + (tt + 1) * 2048 + c * 512);
                vpre[c] = *reinterpret_cast<const s16x8*>(
                    vgb + (tt + 1) * 32 + (size_t)c * 65536);
            }
        }

        // ---- QK^T: S^T[32j][32q] over d=64 ----
        const short* kr = Kl + qi * 64;
        f32x16 S = {};
        setprio1();
        #pragma unroll
        for (int m = 0; m < 4; ++m) {
            const s16x8 a = *reinterpret_cast<const s16x8*>(
                kr + (((2 * m + hi) ^ rx) * 8));
            S = mfma3216(a, qf[m], S);
        }
        setprio0();

        // ---- V frags (80B rows; chunk (2s+hi), no XOR needed) ----
        const short* vr0 = Vl + qi * 40;
        const short* vr1 = Vl + (32 + qi) * 40;
        const s16x8 va00 = *reinterpret_cast<const s16x8*>(vr0 + hi * 8);
        const s16x8 va10 = *reinterpret_cast<const s16x8*>(vr1 + hi * 8);
        const s16x8 va01 = *reinterpret_cast<const s16x8*>(vr0 + (2 + hi) * 8);
        const s16x8 va11 = *reinterpret_cast<const s16x8*>(vr1 + (2 + hi) * 8);

        // ---- P = exp2(S) (fixed max), pack, accumulate l ----
        unsigned Pu[8];
        float ps = 0.0f;
        #pragma unroll
        for (int i = 0; i < 8; ++i) {
            const float e0 = fast_exp2(S[2 * i]);
            const float e1 = fast_exp2(S[2 * i + 1]);
            ps += e0 + e1;
            Pu[i] = cvt_pk_bf16(e0, e1);
        }
        lsum += ps;
        const u32x4 w0 = {Pu[0], Pu[1], Pu[2], Pu[3]};
        const u32x4 w1 = {Pu[4], Pu[5], Pu[6], Pu[7]};

        // ---- PV (exchange-free; permuted V matches P j-order) ----
        setprio1();
        oacc0 = mfma3216(va00, __builtin_bit_cast(s16x8, w0), oacc0);
        oacc1 = mfma3216(va10, __builtin_bit_cast(s16x8, w0), oacc1);
        oacc0 = mfma3216(va01, __builtin_bit_cast(s16x8, w1), oacc0);
        oacc1 = mfma3216(va11, __builtin_bit_cast(s16x8, w1), oacc1);
        setprio0();

        // ---- stage next tile into the other (wave-private) buffer ----
        if (tt < 31) {
            short* Kd = Kbuf + (cur ^ 1) * 2048;
            short* Vd = Vbuf + (cur ^ 1) * 2560;
            #pragma unroll
            for (int c = 0; c < 4; ++c) {
                *reinterpret_cast<s16x8*>(&Kd[kdoff[c]]) = kpre[c];
                s16x4 vlo = {vpre[c][0], vpre[c][1], vpre[c][2], vpre[c][3]};
                s16x4 vhi = {vpre[c][4], vpre[c][5], vpre[c][6], vpre[c][7]};
                *reinterpret_cast<s16x4*>(&Vd[vdoff0[c]]) = vlo;
                *reinterpret_cast<s16x4*>(&Vd[vdoff1[c]]) = vhi;
            }
        }
        // NO __syncthreads: buffers are wave-private.
    }

    // total l for this q over this stream (both hi halves)
    const float ltot = lsum + __shfl_xor(lsum, 32);

    // ---- epilogue: all waves done -> overlay merge arrays on LDS ----
    __syncthreads();
    float* Of = reinterpret_cast<float*>(SM);     // [256 rows][65 f32]
    float* Lf = Of + 256 * 65;                    // [256]
    {
        const int rowb = (kw * 64 + qw * 32 + qi) * 65;
        #pragma unroll
        for (int db = 0; db < 2; ++db) {
            const f32x16 oa = db ? oacc1 : oacc0;
            #pragma unroll
            for (int r = 0; r < 16; ++r) {
                const int d = (r & 3) + 8 * (r >> 2) + 4 * hi + 32 * db;
                Of[rowb + d] = oa[r];
            }
        }
        if (hi == 0) Lf[kw * 64 + qw * 32 + qi] = ltot;
    }
    __syncthreads();

    // ---- final: sum 4 streams, normalize, add residual, write out ----
    {
        const int d  = t >> 3;          // 0..63
        const int q8 = (t & 7) * 8;     // 8 consecutive q
        float res[8];
        #pragma unroll
        for (int i = 0; i < 8; ++i) {
            const int rb = q8 + i;      // 0..63
            const float L = Lf[rb] + Lf[64 + rb] + Lf[128 + rb] + Lf[192 + rb];
            const float o = Of[(rb)       * 65 + d] + Of[(64 + rb)  * 65 + d] +
                            Of[(128 + rb) * 65 + d] + Of[(192 + rb) * 65 + d];
            res[i] = o / L;
        }
        const size_t ob = ((size_t)b * 64 + d) * 4096 + qt * 64 + q8;
        const float4 x0 = *reinterpret_cast<const float4*>(x + ob);
        const float4 x1 = *reinterpret_cast<const float4*>(x + ob + 4);
        float4 o0 = {res[0] + x0.x, res[1] + x0.y, res[2] + x0.z, res[3] + x0.w};
        float4 o1 = {res[4] + x1.x, res[5] + x1.y, res[6] + x1.z, res[7] + x1.w};
        *reinterpret_cast<float4*>(out + ob)     = o0;
        *reinterpret_cast<float4*>(out + ob + 4) = o1;
    }
}

extern "C" void kernel_launch(void* const* d_in, const int* in_sizes, int n_in,
                              void* d_out, int out_size, void* d_ws, size_t ws_size,
                              hipStream_t stream) {
    const float* x  = (const float*)d_in[0];
    const float* wq = (const float*)d_in[1];
    const float* bq = (const float*)d_in[2];
    const float* wk = (const float*)d_in[3];
    const float* bk = (const float*)d_in[4];
    const float* wv = (const float*)d_in[5];
    const float* bv = (const float*)d_in[6];
    float* out = (float*)d_out;

    short* Qg  = reinterpret_cast<short*>(d_ws);   // [4][4096][64]  2MB
    short* Kg  = Qg  + (size_t)4 * 4096 * 64;      // [4][4096][64]  2MB
    short* Vtg = Kg  + (size_t)4 * 4096 * 64;      // [4][64][4096]  2MB

    qkv_proj<<<dim3(512), dim3(512), 0, stream>>>(x, wq, bq, wk, bk, wv, bv, Qg, Kg, Vtg);
    attn_fused<<<dim3(256), dim3(512), 0, stream>>>(Qg, Kg, Vtg, x, out);
}